// Round 9
// baseline (43807.870 us; speedup 1.0000x reference)
//
#include <hip/hip_runtime.h>

#define Tq 256
#define Sq 512
#define Hq 512
#define H2q 1024
#define KPACK 1664   // trg(128) | outs(512) | ctx(1024)

typedef __attribute__((ext_vector_type(8))) short short8_t;
typedef __attribute__((ext_vector_type(4))) float f32x4;

__device__ __forceinline__ float bf2f(ushort u){ return __uint_as_float(((unsigned)u)<<16); }
__device__ __forceinline__ ushort f2bf(float f){
  unsigned u = __float_as_uint(f);
  u += 0x7FFFu + ((u>>16)&1u);
  return (ushort)(u>>16);
}
__device__ __forceinline__ float frcp(float x){ return __builtin_amdgcn_rcpf(x); }
__device__ __forceinline__ float ftanh(float x){
  x = fminf(fmaxf(x, -15.f), 15.f);
  float u = __expf(x + x);
  return (u - 1.f) * frcp(u + 1.f);
}
__device__ __forceinline__ float fsig(float x){
  return frcp(1.f + __expf(-x));
}

// contention-free cluster barrier primitives
__device__ __forceinline__ void wait32(const unsigned* f, unsigned target, int tid){
  if (tid < 32) {
    while (__hip_atomic_load(&f[tid], __ATOMIC_ACQUIRE, __HIP_MEMORY_SCOPE_AGENT) < target)
      __builtin_amdgcn_s_sleep(1);
  }
  __syncthreads();
}

// ---------------- guard bail (f32 out) ----------------
__global__ void bail_kernel(float* out, float v){
  if (threadIdx.x < 256) out[threadIdx.x] = v;
}

__global__ void flags_init(unsigned* f){
  if (threadIdx.x < 512) f[threadIdx.x] = 0u;
}

// ---------------- conversion kernels ----------------
__global__ void conv_bf16(const float* __restrict__ src, ushort* __restrict__ dst, int n4){
  int idx = blockIdx.x*blockDim.x + threadIdx.x;
  if (idx >= n4) return;
  float4 v = ((const float4*)src)[idx];
  ushort4 o; o.x = f2bf(v.x); o.y = f2bf(v.y); o.z = f2bf(v.z); o.w = f2bf(v.w);
  ((ushort4*)dst)[idx] = o;
}

__global__ void pack_trg(const float* __restrict__ trg, ushort* __restrict__ packed, int n4){
  int idx = blockIdx.x*blockDim.x + threadIdx.x;
  if (idx >= n4) return;                 // n4 = B*T*E/4
  float4 v = ((const float4*)trg)[idx];
  int bt = idx >> 5, r = idx & 31;       // E/4 = 32
  ushort4 o; o.x = f2bf(v.x); o.y = f2bf(v.y); o.z = f2bf(v.z); o.w = f2bf(v.w);
  *(ushort4*)&packed[(long)bt*KPACK + r*4] = o;
}

__global__ void bsum_kernel(const float* __restrict__ a, const float* __restrict__ b,
                            float* __restrict__ o, int n){
  int idx = blockIdx.x*blockDim.x + threadIdx.x;
  if (idx < n) o[idx] = a[idx] + b[idx];
}

// ---------------- bridge ----------------
__global__ __launch_bounds__(512)
void bridge_kernel(const float* __restrict__ efh, const float* __restrict__ efc,
                   const float* __restrict__ bhw, const float* __restrict__ bhb,
                   const float* __restrict__ bcw, const float* __restrict__ bcb,
                   float* __restrict__ hb0, float* __restrict__ cws)
{
  int b = blockIdx.x, n = threadIdx.x;
  __shared__ __align__(16) float eh_l[1024];
  __shared__ __align__(16) float ec_l[1024];
  eh_l[n]       = efh[b*1024 + n];
  eh_l[n + 512] = efh[b*1024 + 512 + n];
  ec_l[n]       = efc[b*1024 + n];
  ec_l[n + 512] = efc[b*1024 + 512 + n];
  __syncthreads();
  const float4* wh = (const float4*)(bhw + (long)n*1024);
  const float4* wc = (const float4*)(bcw + (long)n*1024);
  float ah = bhb[n], ac = bcb[n];
  for (int i = 0; i < 256; ++i) {
    float4 w1 = wh[i]; float4 w2 = wc[i];
    const float* e1 = &eh_l[i*4]; const float* e2 = &ec_l[i*4];
    ah += w1.x*e1[0] + w1.y*e1[1] + w1.z*e1[2] + w1.w*e1[3];
    ac += w2.x*e2[0] + w2.y*e2[1] + w2.z*e2[2] + w2.w*e2[3];
  }
  hb0[b*512 + n] = ftanh(ah);
  cws[b*512 + n] = ftanh(ac);
}

// ---------------- MFMA BT-GEMM: C[m,n] = sum_k A[m,k]*Bt[n,k] ----------------
__global__ __launch_bounds__(256)
void gemm_bt(const ushort* __restrict__ A, int lda, long sA,
             const ushort* __restrict__ Bt, int ldb, long sB,
             void* __restrict__ Cout, int ldc, long sC, int K, int outBf16)
{
  __shared__ __align__(16) ushort Al[128][40];
  __shared__ __align__(16) ushort Bl[128][40];
  int bz = blockIdx.z;
  const ushort* Ab = A + (long)bz*sA;
  const ushort* Bb = Bt + (long)bz*sB;
  int m0 = blockIdx.x*128, n0 = blockIdx.y*128;
  int tid = threadIdx.x;
  int lane = tid & 63, w = tid >> 6;
  int wm = w >> 1, wn = w & 1;
  f32x4 acc[4][4] = {};
  int frow = lane & 15, fk = (lane >> 4)*8;
  for (int k0 = 0; k0 < K; k0 += 32) {
    #pragma unroll
    for (int p = 0; p < 2; ++p) {
      int task = tid + p*256;
      int row = task >> 2, c8 = (task & 3)*8;
      uint4 va = *(const uint4*)(Ab + (long)(m0+row)*lda + k0 + c8);
      uint4 vb = *(const uint4*)(Bb + (long)(n0+row)*ldb + k0 + c8);
      *(uint4*)&Al[row][c8] = va;
      *(uint4*)&Bl[row][c8] = vb;
    }
    __syncthreads();
    short8_t af[4], bfr[4];
    #pragma unroll
    for (int mi = 0; mi < 4; ++mi) af[mi]  = *(const short8_t*)&Al[wm*64 + mi*16 + frow][fk];
    #pragma unroll
    for (int ni = 0; ni < 4; ++ni) bfr[ni] = *(const short8_t*)&Bl[wn*64 + ni*16 + frow][fk];
    #pragma unroll
    for (int mi = 0; mi < 4; ++mi)
      #pragma unroll
      for (int ni = 0; ni < 4; ++ni)
        acc[mi][ni] = __builtin_amdgcn_mfma_f32_16x16x32_bf16(af[mi], bfr[ni], acc[mi][ni], 0, 0, 0);
    __syncthreads();
  }
  int rbase = (lane >> 4)*4;
  int col = lane & 15;
  #pragma unroll
  for (int mi = 0; mi < 4; ++mi)
    #pragma unroll
    for (int ni = 0; ni < 4; ++ni)
      #pragma unroll
      for (int i = 0; i < 4; ++i) {
        int gm = m0 + wm*64 + mi*16 + rbase + i;
        int gn = n0 + wn*64 + ni*16 + col;
        float vv = acc[mi][ni][i];
        if (outBf16) ((ushort*)Cout)[(long)bz*sC + (long)gm*ldc + gn] = f2bf(vv);
        else         ((float* )Cout)[(long)bz*sC + (long)gm*ldc + gn] = vv;
      }
}

// ---------------- persistent fused scan: flag-based cluster sync ----------------
__global__ __launch_bounds__(512)
void scan_fused(const ushort* __restrict__ pkT,
                const ushort* __restrict__ ehb,
                ushort* __restrict__ packed,
                const ushort* __restrict__ Wq,
                const ushort* __restrict__ Wih,
                const ushort* __restrict__ Whh,
                const float* __restrict__ bsum,
                const float* __restrict__ vatt,
                float* __restrict__ hb0,
                float* __restrict__ hb1,
                float* __restrict__ cws,
                float* __restrict__ ctxp0,
                float* __restrict__ ctxp1,
                float* __restrict__ denp,
                unsigned* __restrict__ flagA,
                unsigned* __restrict__ flagB,
                float* __restrict__ outs)
{
  __shared__ union {
    struct {
      float h_s[512]; float v_s[512]; float q_s[512]; float sred[512];
      float e_s[128]; float redd[2];
    } a;
    struct {
      float  x_lds[8*KPACK];
      ushort W_lds[64*128];
      float  redc[4096];
      float  g_lds[512];
      float  rden[8];
    } c;
  } sm;

  int tid = threadIdx.x, blk = blockIdx.x;
  int lane = tid & 63, wv = tid >> 6;
  int a_b = blk >> 2, a_j = blk & 3, s0 = a_j*128;   // phase A role
  int c_bg = blk >> 5, c_rc = blk & 31;              // phase B role
  int cluster = blk >> 5;

  for (int t = 0; t < Tq; ++t) {
    int par = t & 1;
    const float* hr = par ? hb1 : hb0;
    float*       hw = par ? hb0 : hb1;
    float* ctxp = par ? ctxp1 : ctxp0;
    float* denq = denp + par*256;

    // ===== Phase A: q + full scores for 128 s + exp + ctx/denom partials =====
    if (t > 0) wait32(flagB + cluster*32, (unsigned)t, tid);
    {
      sm.a.h_s[tid] = hr[a_b*Hq + tid];
      sm.a.v_s[tid] = vatt[tid];
      __syncthreads();
      // q[n=tid] = sum_k h[k]*Wq[n,k]
      {
        const ushort* wrow = Wq + (long)tid*Hq;
        float qa = 0.f;
        #pragma unroll 4
        for (int k = 0; k < 512; k += 8) {
          uint4 w4 = *(const uint4*)(wrow + k);
          const ushort* wu = (const ushort*)&w4;
          #pragma unroll
          for (int e = 0; e < 8; ++e) qa += sm.a.h_s[k+e]*bf2f(wu[e]);
        }
        sm.a.q_s[tid] = qa;
      }
      __syncthreads();
      // score partial: thread (hg, sl) covers 128 h for s = s0+sl
      int sl = tid & 127, hg = tid >> 7;
      {
        const ushort* pkp = pkT + ((long)a_b*Hq + hg*128)*Sq + s0 + sl;
        float p = 0.f;
        #pragma unroll 4
        for (int hh = 0; hh < 128; ++hh)
          p += sm.a.v_s[hg*128+hh]*ftanh(bf2f(pkp[(long)hh*Sq]) + sm.a.q_s[hg*128+hh]);
        sm.a.sred[hg*128 + sl] = p;
      }
      __syncthreads();
      if (tid < 128) {
        float sc = sm.a.sred[tid] + sm.a.sred[128+tid] + sm.a.sred[256+tid] + sm.a.sred[384+tid];
        float e = __expf(sc);
        sm.a.e_s[tid] = e;
        float r = e;
        #pragma unroll
        for (int off = 32; off; off >>= 1) r += __shfl_down(r, off);
        if ((tid & 63) == 0) sm.a.redd[tid >> 6] = r;
      }
      __syncthreads();
      if (tid == 0) denq[a_b*4 + a_j] = sm.a.redd[0] + sm.a.redd[1];
      // unnormalized ctx partial over this s-quarter, all 1024 k
      for (int kk = tid; kk < 1024; kk += 512) {
        const ushort* ep = ehb + ((long)a_b*Sq + s0)*H2q + kk;
        float acc = 0.f;
        #pragma unroll 4
        for (int s = 0; s < 128; ++s)
          acc += sm.a.e_s[s]*bf2f(ep[(long)s*H2q]);
        ctxp[((long)a_b*4 + a_j)*1024 + kk] = acc;
      }
    }
    __threadfence();
    __syncthreads();
    if (tid == 0)
      __hip_atomic_store(&flagA[blk], (unsigned)(t+1), __ATOMIC_RELEASE, __HIP_MEMORY_SCOPE_AGENT);

    // ===== Phase B: gates GEMM (8 b per block) + LSTM pointwise =====
    {
      // trg region of x (independent of phase A output)
      for (int task = tid; task < 128; task += 512) {
        int bb = task >> 4, c8 = task & 15;
        int gb = c_bg*8 + bb;
        uint4 vv = *(const uint4*)(packed + (long)(gb*Tq + t)*KPACK + c8*8);
        const ushort* uu = (const ushort*)&vv;
        #pragma unroll
        for (int e = 0; e < 8; ++e) sm.c.x_lds[bb*KPACK + c8*8 + e] = bf2f(uu[e]);
      }
      // h region of x
      for (int task = tid; task < 4096; task += 512) {
        int bb = task >> 9, kk = task & 511;
        sm.c.x_lds[bb*KPACK + 1152 + kk] = hr[(c_bg*8 + bb)*Hq + kk];
      }
      wait32(flagA + cluster*32, (unsigned)(t+1), tid);
      if (tid < 8) {
        int gb = c_bg*8 + tid;
        sm.c.rden[tid] = frcp(denq[gb*4+0] + denq[gb*4+1] + denq[gb*4+2] + denq[gb*4+3]);
      }
      __syncthreads();   // rden ready
      // ctx region of x (finalize normalization); persist bf16 ctx for pre-GEMM
      for (int task = tid; task < 8192; task += 512) {
        int bb = task >> 10, kk = task & 1023;
        int gb = c_bg*8 + bb;
        float cv = (ctxp[((long)gb*4+0)*1024+kk] + ctxp[((long)gb*4+1)*1024+kk]
                  + ctxp[((long)gb*4+2)*1024+kk] + ctxp[((long)gb*4+3)*1024+kk])*sm.c.rden[bb];
        sm.c.x_lds[bb*KPACK + 128 + kk] = cv;
        if (c_rc == 0) packed[(long)(gb*Tq + t)*KPACK + 640 + kk] = f2bf(cv);
      }
      float acc[8] = {};
      for (int kt = 0; kt < 13; ++kt) {
        __syncthreads();
        #pragma unroll
        for (int p2 = 0; p2 < 2; ++p2) {
          int task = tid + p2*512;
          int row = task >> 4, c8 = (task & 15)*8;
          int rr = (row >> 4)*512 + c_rc*16 + (row & 15);
          const ushort* wsrc = (kt < 9) ? (Wih + (long)rr*1152 + kt*128 + c8)
                                        : (Whh + (long)rr*512  + (kt-9)*128 + c8);
          uint4 w4 = *(const uint4*)wsrc;
          unsigned bo = (unsigned)(row*256 + c8*2) ^ (unsigned)((row & 7) << 4);
          *(uint4*)((char*)sm.c.W_lds + bo) = w4;
        }
        __syncthreads();
        int kk = wv*16;
        int xbase = kt*128 + kk;
        #pragma unroll
        for (int c = 0; c < 2; ++c) {
          unsigned bo = (unsigned)(lane*256 + (kk + c*8)*2) ^ (unsigned)((lane & 7) << 4);
          uint4 w4 = *(const uint4*)((const char*)sm.c.W_lds + bo);
          const ushort* wu = (const ushort*)&w4;
          float wf[8];
          #pragma unroll
          for (int e = 0; e < 8; ++e) wf[e] = bf2f(wu[e]);
          #pragma unroll
          for (int bb = 0; bb < 8; ++bb) {
            const float* xp = &sm.c.x_lds[bb*KPACK + xbase + c*8];
            float4 x0 = *(const float4*)xp;
            float4 x1 = *(const float4*)(xp + 4);
            acc[bb] += wf[0]*x0.x + wf[1]*x0.y + wf[2]*x0.z + wf[3]*x0.w
                     + wf[4]*x1.x + wf[5]*x1.y + wf[6]*x1.z + wf[7]*x1.w;
          }
        }
      }
      __syncthreads();
      #pragma unroll
      for (int bb = 0; bb < 8; ++bb)
        sm.c.redc[(wv*8 + bb)*64 + lane] = acc[bb];
      __syncthreads();
      {
        int rl2 = tid & 63, bb = tid >> 6;
        float gvv = bsum[(rl2 >> 4)*512 + c_rc*16 + (rl2 & 15)];
        #pragma unroll
        for (int q2 = 0; q2 < 8; ++q2) gvv += sm.c.redc[(q2*8 + bb)*64 + rl2];
        sm.c.g_lds[bb*64 + rl2] = gvv;
      }
      __syncthreads();
      if (tid < 128) {
        int bb = tid >> 4, i2 = tid & 15;
        int gb = c_bg*8 + bb;
        int hd = c_rc*16 + i2;
        float gi = sm.c.g_lds[bb*64 +  0 + i2];
        float gf = sm.c.g_lds[bb*64 + 16 + i2];
        float gg = sm.c.g_lds[bb*64 + 32 + i2];
        float go = sm.c.g_lds[bb*64 + 48 + i2];
        float co = cws[gb*Hq + hd];
        float cn = fsig(gf)*co + fsig(gi)*ftanh(gg);
        float hn = fsig(go)*ftanh(cn);
        cws[gb*Hq + hd] = cn;
        hw[gb*Hq + hd] = hn;
        outs[(long)(gb*Tq + t)*Hq + hd] = hn;
        packed[(long)(gb*Tq + t)*KPACK + 128 + hd] = f2bf(hn);
      }
    }
    __threadfence();
    __syncthreads();
    if (tid == 0)
      __hip_atomic_store(&flagB[blk], (unsigned)(t+1), __ATOMIC_RELEASE, __HIP_MEMORY_SCOPE_AGENT);
  }
}

__global__ void epilogue_copy(const float* __restrict__ hb0, const float* __restrict__ cws,
                              float* __restrict__ dout){
  int idx = blockIdx.x*blockDim.x + threadIdx.x;
  if (idx < 32768) {
    dout[8388608 + idx] = hb0[idx];
    dout[8421376 + idx] = cws[idx];
  }
}

extern "C" void kernel_launch(void* const* d_in, const int* in_sizes, int n_in,
                              void* d_out, int out_size, void* d_ws, size_t ws_size,
                              hipStream_t stream)
{
  float* out = (float*)d_out;
  static const int expect[18] = {2097152,33554432,65536,65536,32768,16384,
                                 524288,262144,512,524288,512,524288,512,
                                 2359296,1048576,2048,2048,851968};
  if (n_in != 18 || out_size != 16842752) {
    bail_kernel<<<1, 256, 0, stream>>>(out, 33.0f); return;
  }
  for (int i = 0; i < 18; ++i) if (in_sizes[i] != expect[i]) {
    bail_kernel<<<1, 256, 0, stream>>>(out, 100.0f + i); return;
  }
  if (ws_size < 166207552ULL) { bail_kernel<<<1, 256, 0, stream>>>(out, 77.0f); return; }

  const float* trg  = (const float*)d_in[0];
  const float* eh   = (const float*)d_in[1];
  const float* efh  = (const float*)d_in[2];
  const float* efc  = (const float*)d_in[3];
  const float* Wk   = (const float*)d_in[6];
  const float* Wq   = (const float*)d_in[7];
  const float* v    = (const float*)d_in[8];
  const float* bhw  = (const float*)d_in[9];
  const float* bhb  = (const float*)d_in[10];
  const float* bcw  = (const float*)d_in[11];
  const float* bcb  = (const float*)d_in[12];
  const float* Wih  = (const float*)d_in[13];
  const float* Whh  = (const float*)d_in[14];
  const float* bih  = (const float*)d_in[15];
  const float* bhh  = (const float*)d_in[16];
  const float* Wpre = (const float*)d_in[17];
  char* ws = (char*)d_ws;

  ushort* ehb    = (ushort*)(ws + 0);
  ushort* pkT    = (ushort*)(ws + 67108864);
  ushort* packed = (ushort*)(ws + 100663296);
  ushort* Wk_b   = (ushort*)(ws + 155189248);
  ushort* Wq_b   = (ushort*)(ws + 156237824);
  ushort* Wih_b  = (ushort*)(ws + 156762112);
  ushort* Whh_b  = (ushort*)(ws + 161480704);
  ushort* Wpre_b = (ushort*)(ws + 163577856);
  // ctxp double buffers: buf0 overlays dead Wk_b slot, buf1 overlays Wpre_b slot
  float*  ctxp0  = (float*)(ws + 155189248);
  float*  ctxp1  = (float*)(ws + 163577856);
  float*  bsum   = (float*)(ws + 165281792);
  float*  hb0    = (float*)(ws + 165289984);
  float*  hb1    = (float*)(ws + 165421056);
  float*  cws    = (float*)(ws + 165552128);
  float*  denp   = (float*)(ws + 165683200);            // 2*256 f32
  unsigned* flagA = (unsigned*)(ws + 165685248);        // 256 u32
  unsigned* flagB = (unsigned*)(ws + 165686272);        // 256 u32

  auto cb = [&](const float* s, ushort* d, int n){
    int n4 = n/4;
    conv_bf16<<<(n4 + 255)/256, 256, 0, stream>>>(s, d, n4);
  };
  cb(eh,   ehb,   64*512*1024);
  cb(Wk,   Wk_b,  512*1024);
  cb(Wq,   Wq_b,  512*512);
  cb(Wih,  Wih_b, 2048*1152);
  cb(Whh,  Whh_b, 2048*512);
  pack_trg<<<(524288 + 255)/256, 256, 0, stream>>>(trg, packed, 524288);
  bsum_kernel<<<8, 256, 0, stream>>>(bih, bhh, bsum, 2048);
  bridge_kernel<<<64, 512, 0, stream>>>(efh, efc, bhw, bhb, bcw, bcb, hb0, cws);
  flags_init<<<1, 512, 0, stream>>>(flagA);   // zeroes flagA+flagB (contiguous 512 u32)
  // proj_key^T[b][h][s] = sum_k Wk[h,k] * eh[b,s,k]
  gemm_bt<<<dim3(4,4,64), 256, 0, stream>>>(Wk_b, 1024, 0L, ehb, 1024, 524288L,
                                            (void*)pkT, 512, 262144L, 1024, 1);

  {
    void* args[] = { (void*)&pkT, (void*)&ehb, (void*)&packed, (void*)&Wq_b,
                     (void*)&Wih_b, (void*)&Whh_b, (void*)&bsum, (void*)&v,
                     (void*)&hb0, (void*)&hb1, (void*)&cws,
                     (void*)&ctxp0, (void*)&ctxp1, (void*)&denp,
                     (void*)&flagA, (void*)&flagB, (void*)&out };
    hipLaunchCooperativeKernel((void*)scan_fused, dim3(256), dim3(512), args, 0, stream);
  }

  // Wpre conversion (its slot was ctxp1 during the scan)
  cb(Wpre, Wpre_b, 512*1664);
  epilogue_copy<<<128, 256, 0, stream>>>(hb0, cws, out);
  // pre[(b,t)][n] = sum_k packed[(b,t),k] * Wpre[n,k]  -> f32 output
  gemm_bt<<<dim3(128,4,1), 256, 0, stream>>>(packed, 1664, 0L, Wpre_b, 1664, 0L,
                                             (void*)(out + 8454144), 512, 0L, 1664, 0);
}

// Round 10
// 17081.932 us; speedup vs baseline: 2.5646x; 2.5646x over previous
//
#include <hip/hip_runtime.h>

#define Tq 256
#define Sq 512
#define Hq 512
#define H2q 1024
#define KPACK 1664   // trg(128) | outs(512) | ctx(1024)

typedef __attribute__((ext_vector_type(8))) short short8_t;
typedef __attribute__((ext_vector_type(4))) float f32x4;

__device__ __forceinline__ float bf2f(ushort u){ return __uint_as_float(((unsigned)u)<<16); }
__device__ __forceinline__ ushort f2bf(float f){
  unsigned u = __float_as_uint(f);
  u += 0x7FFFu + ((u>>16)&1u);
  return (ushort)(u>>16);
}
__device__ __forceinline__ float frcp(float x){ return __builtin_amdgcn_rcpf(x); }
__device__ __forceinline__ float ftanh(float x){
  x = fminf(fmaxf(x, -15.f), 15.f);
  float u = __expf(x + x);
  return (u - 1.f) * frcp(u + 1.f);
}
__device__ __forceinline__ float fsig(float x){
  return frcp(1.f + __expf(-x));
}

// ---------------- guard bail (f32 out) ----------------
__global__ void bail_kernel(float* out, float v){
  if (threadIdx.x < 256) out[threadIdx.x] = v;
}

// ---------------- conversion kernels ----------------
__global__ void conv_bf16(const float* __restrict__ src, ushort* __restrict__ dst, int n4){
  int idx = blockIdx.x*blockDim.x + threadIdx.x;
  if (idx >= n4) return;
  float4 v = ((const float4*)src)[idx];
  ushort4 o; o.x = f2bf(v.x); o.y = f2bf(v.y); o.z = f2bf(v.z); o.w = f2bf(v.w);
  ((ushort4*)dst)[idx] = o;
}

__global__ void pack_trg(const float* __restrict__ trg, ushort* __restrict__ packed, int n4){
  int idx = blockIdx.x*blockDim.x + threadIdx.x;
  if (idx >= n4) return;                 // n4 = B*T*E/4
  float4 v = ((const float4*)trg)[idx];
  int bt = idx >> 5, r = idx & 31;       // E/4 = 32
  ushort4 o; o.x = f2bf(v.x); o.y = f2bf(v.y); o.z = f2bf(v.z); o.w = f2bf(v.w);
  *(ushort4*)&packed[(long)bt*KPACK + r*4] = o;
}

__global__ void bsum_kernel(const float* __restrict__ a, const float* __restrict__ b,
                            float* __restrict__ o, int n){
  int idx = blockIdx.x*blockDim.x + threadIdx.x;
  if (idx < n) o[idx] = a[idx] + b[idx];
}

// ---------------- bridge ----------------
__global__ __launch_bounds__(512)
void bridge_kernel(const float* __restrict__ efh, const float* __restrict__ efc,
                   const float* __restrict__ bhw, const float* __restrict__ bhb,
                   const float* __restrict__ bcw, const float* __restrict__ bcb,
                   float* __restrict__ hb0, float* __restrict__ cws)
{
  int b = blockIdx.x, n = threadIdx.x;
  __shared__ __align__(16) float eh_l[1024];
  __shared__ __align__(16) float ec_l[1024];
  eh_l[n]       = efh[b*1024 + n];
  eh_l[n + 512] = efh[b*1024 + 512 + n];
  ec_l[n]       = efc[b*1024 + n];
  ec_l[n + 512] = efc[b*1024 + 512 + n];
  __syncthreads();
  const float4* wh = (const float4*)(bhw + (long)n*1024);
  const float4* wc = (const float4*)(bcw + (long)n*1024);
  float ah = bhb[n], ac = bcb[n];
  for (int i = 0; i < 256; ++i) {
    float4 w1 = wh[i]; float4 w2 = wc[i];
    const float* e1 = &eh_l[i*4]; const float* e2 = &ec_l[i*4];
    ah += w1.x*e1[0] + w1.y*e1[1] + w1.z*e1[2] + w1.w*e1[3];
    ac += w2.x*e2[0] + w2.y*e2[1] + w2.z*e2[2] + w2.w*e2[3];
  }
  hb0[b*512 + n] = ftanh(ah);
  cws[b*512 + n] = ftanh(ac);
}

// ---------------- MFMA BT-GEMM: C[m,n] = sum_k A[m,k]*Bt[n,k] ----------------
// outMode: 0 = f32, 1 = bf16, 2 = fp8(e4m3)
__global__ __launch_bounds__(256)
void gemm_bt(const ushort* __restrict__ A, int lda, long sA,
             const ushort* __restrict__ Bt, int ldb, long sB,
             void* __restrict__ Cout, int ldc, long sC, int K, int outMode)
{
  __shared__ __align__(16) ushort Al[128][40];
  __shared__ __align__(16) ushort Bl[128][40];
  int bz = blockIdx.z;
  const ushort* Ab = A + (long)bz*sA;
  const ushort* Bb = Bt + (long)bz*sB;
  int m0 = blockIdx.x*128, n0 = blockIdx.y*128;
  int tid = threadIdx.x;
  int lane = tid & 63, w = tid >> 6;
  int wm = w >> 1, wn = w & 1;
  f32x4 acc[4][4] = {};
  int frow = lane & 15, fk = (lane >> 4)*8;
  for (int k0 = 0; k0 < K; k0 += 32) {
    #pragma unroll
    for (int p = 0; p < 2; ++p) {
      int task = tid + p*256;
      int row = task >> 2, c8 = (task & 3)*8;
      uint4 va = *(const uint4*)(Ab + (long)(m0+row)*lda + k0 + c8);
      uint4 vb = *(const uint4*)(Bb + (long)(n0+row)*ldb + k0 + c8);
      *(uint4*)&Al[row][c8] = va;
      *(uint4*)&Bl[row][c8] = vb;
    }
    __syncthreads();
    short8_t af[4], bfr[4];
    #pragma unroll
    for (int mi = 0; mi < 4; ++mi) af[mi]  = *(const short8_t*)&Al[wm*64 + mi*16 + frow][fk];
    #pragma unroll
    for (int ni = 0; ni < 4; ++ni) bfr[ni] = *(const short8_t*)&Bl[wn*64 + ni*16 + frow][fk];
    #pragma unroll
    for (int mi = 0; mi < 4; ++mi)
      #pragma unroll
      for (int ni = 0; ni < 4; ++ni)
        acc[mi][ni] = __builtin_amdgcn_mfma_f32_16x16x32_bf16(af[mi], bfr[ni], acc[mi][ni], 0, 0, 0);
    __syncthreads();
  }
  int rbase = (lane >> 4)*4;
  int col = lane & 15;
  #pragma unroll
  for (int mi = 0; mi < 4; ++mi)
    #pragma unroll
    for (int ni = 0; ni < 4; ++ni)
      #pragma unroll
      for (int i = 0; i < 4; ++i) {
        int gm = m0 + wm*64 + mi*16 + rbase + i;
        int gn = n0 + wn*64 + ni*16 + col;
        float vv = acc[mi][ni][i];
        long off = (long)bz*sC + (long)gm*ldc + gn;
        if (outMode == 1)      ((ushort*)Cout)[off] = f2bf(vv);
        else if (outMode == 2) ((unsigned char*)Cout)[off] =
              (unsigned char)(__builtin_amdgcn_cvt_pk_fp8_f32(vv, 0.f, 0, false) & 0xFF);
        else                   ((float*)Cout)[off] = vv;
      }
}

// ---------------- scan phase A: q + scores(fp8 pk) + exp + ctx partials ----------------
// pk8 layout: [b][s][h] fp8 e4m3
__global__ __launch_bounds__(512)
void scanA2(const unsigned char* __restrict__ pk8,
            const ushort* __restrict__ ehb,
            const ushort* __restrict__ Wq,
            const float* __restrict__ vatt,
            const float* __restrict__ hr,
            float* __restrict__ ctxp,
            float* __restrict__ denp)
{
  __shared__ __align__(16) float h_s[512];
  __shared__ __align__(16) float v_s[512];
  __shared__ __align__(16) float q_s[512];
  __shared__ __align__(16) float sred[512];
  __shared__ __align__(16) float e_s[128];
  __shared__ __align__(16) float redd[2];
  int tid = threadIdx.x, blk = blockIdx.x;
  int b = blk >> 2, j = blk & 3, s0 = j*128;
  h_s[tid] = hr[b*Hq + tid];
  v_s[tid] = vatt[tid];
  __syncthreads();
  // q[n=tid] = sum_k h[k]*Wq[n,k]
  {
    const ushort* wrow = Wq + (long)tid*Hq;
    float qa = 0.f;
    #pragma unroll 4
    for (int k = 0; k < 512; k += 8) {
      uint4 w4 = *(const uint4*)(wrow + k);
      const ushort* wu = (const ushort*)&w4;
      #pragma unroll
      for (int e = 0; e < 8; ++e) qa += h_s[k+e]*bf2f(wu[e]);
    }
    q_s[tid] = qa;
  }
  __syncthreads();
  // scores: 4 threads per s (h-quarters), wide fp8 loads along h
  int sl = tid & 127, hq = tid >> 7;
  {
    const unsigned char* pr = pk8 + ((long)b*Sq + s0 + sl)*Hq + hq*128;
    float p = 0.f;
    #pragma unroll
    for (int i = 0; i < 8; ++i) {
      uint4 w4 = *(const uint4*)(pr + i*16);
      const unsigned* uw = (const unsigned*)&w4;
      #pragma unroll
      for (int m = 0; m < 4; ++m) {
        unsigned u = uw[m];
        int hb = hq*128 + i*16 + m*4;
        p += v_s[hb+0]*ftanh(__builtin_amdgcn_cvt_f32_fp8(u,0) + q_s[hb+0]);
        p += v_s[hb+1]*ftanh(__builtin_amdgcn_cvt_f32_fp8(u,1) + q_s[hb+1]);
        p += v_s[hb+2]*ftanh(__builtin_amdgcn_cvt_f32_fp8(u,2) + q_s[hb+2]);
        p += v_s[hb+3]*ftanh(__builtin_amdgcn_cvt_f32_fp8(u,3) + q_s[hb+3]);
      }
    }
    sred[hq*128 + sl] = p;
  }
  __syncthreads();
  if (tid < 128) {
    float sc = sred[tid] + sred[128+tid] + sred[256+tid] + sred[384+tid];
    float e = __expf(sc);
    e_s[tid] = e;
    float r = e;
    #pragma unroll
    for (int off = 32; off; off >>= 1) r += __shfl_down(r, off);
    if ((tid & 63) == 0) redd[tid >> 6] = r;
  }
  __syncthreads();
  if (tid == 0) denp[b*4 + j] = redd[0] + redd[1];
  // unnormalized ctx partial: each thread owns kk = 2*tid, 2*tid+1
  {
    const ushort* ep = ehb + ((long)b*Sq + s0)*H2q + tid*2;
    float a0 = 0.f, a1 = 0.f;
    #pragma unroll 4
    for (int s = 0; s < 128; ++s) {
      unsigned u = *(const unsigned*)(ep + (long)s*H2q);
      float es = e_s[s];
      a0 += es*bf2f((ushort)(u & 0xFFFF));
      a1 += es*bf2f((ushort)(u >> 16));
    }
    float* cp = ctxp + ((long)b*4 + j)*1024 + tid*2;
    cp[0] = a0; cp[1] = a1;
  }
}

// ---------------- scan phase B: normalize ctx + gates GEMM + LSTM ----------------
__global__ __launch_bounds__(512)
void scanB2(int t, ushort* packed,
            const ushort* __restrict__ Wih, const ushort* __restrict__ Whh,
            const float* __restrict__ bsum, const float* __restrict__ hr,
            float* __restrict__ hw, float* __restrict__ cws,
            const float* __restrict__ ctxp, const float* __restrict__ denp,
            float* __restrict__ outs)
{
  __shared__ __align__(16) float  x_lds[8*KPACK];
  __shared__ __align__(16) ushort W_lds[64*128];
  __shared__ __align__(16) float  redc[4096];
  __shared__ __align__(16) float  g_lds[512];
  __shared__ __align__(16) float  rden[8];
  int tid = threadIdx.x, blk = blockIdx.x;
  int lane = tid & 63, wv = tid >> 6;
  int c_bg = blk >> 5, c_rc = blk & 31;

  if (tid < 8) {
    int gb = c_bg*8 + tid;
    rden[tid] = frcp(denp[gb*4+0] + denp[gb*4+1] + denp[gb*4+2] + denp[gb*4+3]);
  }
  // trg region of x
  for (int task = tid; task < 128; task += 512) {
    int bb = task >> 4, c8 = task & 15;
    int gb = c_bg*8 + bb;
    uint4 vv = *(const uint4*)(packed + (long)(gb*Tq + t)*KPACK + c8*8);
    const ushort* uu = (const ushort*)&vv;
    #pragma unroll
    for (int e = 0; e < 8; ++e) x_lds[bb*KPACK + c8*8 + e] = bf2f(uu[e]);
  }
  // h region of x
  for (int task = tid; task < 4096; task += 512) {
    int bb = task >> 9, kk = task & 511;
    x_lds[bb*KPACK + 1152 + kk] = hr[(c_bg*8 + bb)*Hq + kk];
  }
  __syncthreads();   // rden ready
  // ctx region of x (normalize); persist bf16 ctx for pre-GEMM
  for (int task = tid; task < 8192; task += 512) {
    int bb = task >> 10, kk = task & 1023;
    int gb = c_bg*8 + bb;
    float cv = (ctxp[((long)gb*4+0)*1024+kk] + ctxp[((long)gb*4+1)*1024+kk]
              + ctxp[((long)gb*4+2)*1024+kk] + ctxp[((long)gb*4+3)*1024+kk])*rden[bb];
    x_lds[bb*KPACK + 128 + kk] = cv;
    if (c_rc == 0) packed[(long)(gb*Tq + t)*KPACK + 640 + kk] = f2bf(cv);
  }
  float acc[8] = {};
  for (int kt = 0; kt < 13; ++kt) {
    __syncthreads();
    #pragma unroll
    for (int p2 = 0; p2 < 2; ++p2) {
      int task = tid + p2*512;
      int row = task >> 4, c8 = (task & 15)*8;
      int rr = (row >> 4)*512 + c_rc*16 + (row & 15);
      const ushort* wsrc = (kt < 9) ? (Wih + (long)rr*1152 + kt*128 + c8)
                                    : (Whh + (long)rr*512  + (kt-9)*128 + c8);
      uint4 w4 = *(const uint4*)wsrc;
      unsigned bo = (unsigned)(row*256 + c8*2) ^ (unsigned)((row & 7) << 4);
      *(uint4*)((char*)W_lds + bo) = w4;
    }
    __syncthreads();
    int kk = wv*16;
    int xbase = kt*128 + kk;
    #pragma unroll
    for (int c = 0; c < 2; ++c) {
      unsigned bo = (unsigned)(lane*256 + (kk + c*8)*2) ^ (unsigned)((lane & 7) << 4);
      uint4 w4 = *(const uint4*)((const char*)W_lds + bo);
      const ushort* wu = (const ushort*)&w4;
      float wf[8];
      #pragma unroll
      for (int e = 0; e < 8; ++e) wf[e] = bf2f(wu[e]);
      #pragma unroll
      for (int bb = 0; bb < 8; ++bb) {
        const float* xp = &x_lds[bb*KPACK + xbase + c*8];
        float4 x0 = *(const float4*)xp;
        float4 x1 = *(const float4*)(xp + 4);
        acc[bb] += wf[0]*x0.x + wf[1]*x0.y + wf[2]*x0.z + wf[3]*x0.w
                 + wf[4]*x1.x + wf[5]*x1.y + wf[6]*x1.z + wf[7]*x1.w;
      }
    }
  }
  __syncthreads();
  #pragma unroll
  for (int bb = 0; bb < 8; ++bb)
    redc[(wv*8 + bb)*64 + lane] = acc[bb];
  __syncthreads();
  {
    int rl2 = tid & 63, bb = tid >> 6;
    float gvv = bsum[(rl2 >> 4)*512 + c_rc*16 + (rl2 & 15)];
    #pragma unroll
    for (int q2 = 0; q2 < 8; ++q2) gvv += redc[(q2*8 + bb)*64 + rl2];
    g_lds[bb*64 + rl2] = gvv;
  }
  __syncthreads();
  if (tid < 128) {
    int bb = tid >> 4, i2 = tid & 15;
    int gb = c_bg*8 + bb;
    int hd = c_rc*16 + i2;
    float gi = g_lds[bb*64 +  0 + i2];
    float gf = g_lds[bb*64 + 16 + i2];
    float gg = g_lds[bb*64 + 32 + i2];
    float go = g_lds[bb*64 + 48 + i2];
    float co = cws[gb*Hq + hd];
    float cn = fsig(gf)*co + fsig(gi)*ftanh(gg);
    float hn = fsig(go)*ftanh(cn);
    cws[gb*Hq + hd] = cn;
    hw[gb*Hq + hd] = hn;
    outs[(long)(gb*Tq + t)*Hq + hd] = hn;
    packed[(long)(gb*Tq + t)*KPACK + 128 + hd] = f2bf(hn);
  }
}

__global__ void epilogue_copy(const float* __restrict__ hb0, const float* __restrict__ cws,
                              float* __restrict__ dout){
  int idx = blockIdx.x*blockDim.x + threadIdx.x;
  if (idx < 32768) {
    dout[8388608 + idx] = hb0[idx];
    dout[8421376 + idx] = cws[idx];
  }
}

extern "C" void kernel_launch(void* const* d_in, const int* in_sizes, int n_in,
                              void* d_out, int out_size, void* d_ws, size_t ws_size,
                              hipStream_t stream)
{
  float* out = (float*)d_out;
  static const int expect[18] = {2097152,33554432,65536,65536,32768,16384,
                                 524288,262144,512,524288,512,524288,512,
                                 2359296,1048576,2048,2048,851968};
  if (n_in != 18 || out_size != 16842752) {
    bail_kernel<<<1, 256, 0, stream>>>(out, 33.0f); return;
  }
  for (int i = 0; i < 18; ++i) if (in_sizes[i] != expect[i]) {
    bail_kernel<<<1, 256, 0, stream>>>(out, 100.0f + i); return;
  }
  if (ws_size < 166207552ULL) { bail_kernel<<<1, 256, 0, stream>>>(out, 77.0f); return; }

  const float* trg  = (const float*)d_in[0];
  const float* eh   = (const float*)d_in[1];
  const float* efh  = (const float*)d_in[2];
  const float* efc  = (const float*)d_in[3];
  const float* Wk   = (const float*)d_in[6];
  const float* Wq   = (const float*)d_in[7];
  const float* v    = (const float*)d_in[8];
  const float* bhw  = (const float*)d_in[9];
  const float* bhb  = (const float*)d_in[10];
  const float* bcw  = (const float*)d_in[11];
  const float* bcb  = (const float*)d_in[12];
  const float* Wih  = (const float*)d_in[13];
  const float* Whh  = (const float*)d_in[14];
  const float* bih  = (const float*)d_in[15];
  const float* bhh  = (const float*)d_in[16];
  const float* Wpre = (const float*)d_in[17];
  char* ws = (char*)d_ws;

  ushort* ehb          = (ushort*)(ws + 0);
  unsigned char* pk8   = (unsigned char*)(ws + 67108864);
  ushort* packed       = (ushort*)(ws + 83886080);
  ushort* Wk_b         = (ushort*)(ws + 138412032);
  ushort* Wq_b         = (ushort*)(ws + 139460608);
  ushort* Wih_b        = (ushort*)(ws + 139984896);
  ushort* Whh_b        = (ushort*)(ws + 144703488);
  ushort* Wpre_b       = (ushort*)(ws + 146800640);
  float*  ctxp         = (float*)(ws + 148504576);
  float*  denp         = (float*)(ws + 149553152);
  float*  bsum         = (float*)(ws + 149554176);
  float*  hb0          = (float*)(ws + 149562368);
  float*  hb1          = (float*)(ws + 149693440);
  float*  cws          = (float*)(ws + 149824512);

  auto cb = [&](const float* s, ushort* d, int n){
    int n4 = n/4;
    conv_bf16<<<(n4 + 255)/256, 256, 0, stream>>>(s, d, n4);
  };
  cb(eh,   ehb,   64*512*1024);
  cb(Wk,   Wk_b,  512*1024);
  cb(Wq,   Wq_b,  512*512);
  cb(Wih,  Wih_b, 2048*1152);
  cb(Whh,  Whh_b, 2048*512);
  cb(Wpre, Wpre_b,512*1664);
  pack_trg<<<(524288 + 255)/256, 256, 0, stream>>>(trg, packed, 524288);
  bsum_kernel<<<8, 256, 0, stream>>>(bih, bhh, bsum, 2048);
  bridge_kernel<<<64, 512, 0, stream>>>(efh, efc, bhw, bhb, bcw, bcb, hb0, cws);
  // pk8[b][s][h] = sum_k eh[b,s,k]*Wk[h,k]  (fp8 e4m3 output)
  gemm_bt<<<dim3(4,4,64), 256, 0, stream>>>(ehb, 1024, 524288L, Wk_b, 1024, 0L,
                                            (void*)pk8, 512, 262144L, 1024, 2);

  for (int t = 0; t < 256; ++t) {
    const float* hr = (t & 1) ? hb1 : hb0;
    float*       hw = (t & 1) ? hb0 : hb1;
    scanA2<<<256, 512, 0, stream>>>(pk8, ehb, Wq_b, v, hr, ctxp, denp);
    scanB2<<<256, 512, 0, stream>>>(t, packed, Wih_b, Whh_b, bsum, hr, hw, cws,
                                    ctxp, denp, out);
  }

  epilogue_copy<<<128, 256, 0, stream>>>(hb0, cws, out);
  // pre[(b,t)][n] = sum_k packed[(b,t),k] * Wpre[n,k]  -> f32 output
  gemm_bt<<<dim3(128,4,1), 256, 0, stream>>>(packed, 1664, 0L, Wpre_b, 1664, 0L,
                                             (void*)(out + 8454144), 512, 0L, 1664, 0);
}

// Round 11
// 14370.522 us; speedup vs baseline: 3.0485x; 1.1887x over previous
//
#include <hip/hip_runtime.h>

#define Tq 256
#define Sq 512
#define Hq 512
#define H2q 1024
#define KPACK 1664   // trg(128) | outs(512) | ctx(1024)

typedef __attribute__((ext_vector_type(8))) short short8_t;
typedef __attribute__((ext_vector_type(4))) float f32x4;

__device__ __forceinline__ float bf2f(ushort u){ return __uint_as_float(((unsigned)u)<<16); }
__device__ __forceinline__ ushort f2bf(float f){
  unsigned u = __float_as_uint(f);
  u += 0x7FFFu + ((u>>16)&1u);
  return (ushort)(u>>16);
}
__device__ __forceinline__ float frcp(float x){ return __builtin_amdgcn_rcpf(x); }
__device__ __forceinline__ float ftanh(float x){
  x = fminf(fmaxf(x, -15.f), 15.f);
  float u = __expf(x + x);
  return (u - 1.f) * frcp(u + 1.f);
}
__device__ __forceinline__ float fsig(float x){
  return frcp(1.f + __expf(-x));
}

// ---------------- guard bail (f32 out) ----------------
__global__ void bail_kernel(float* out, float v){
  if (threadIdx.x < 256) out[threadIdx.x] = v;
}

// ---------------- conversion kernels ----------------
__global__ void conv_bf16(const float* __restrict__ src, ushort* __restrict__ dst, int n4){
  int idx = blockIdx.x*blockDim.x + threadIdx.x;
  if (idx >= n4) return;
  float4 v = ((const float4*)src)[idx];
  ushort4 o; o.x = f2bf(v.x); o.y = f2bf(v.y); o.z = f2bf(v.z); o.w = f2bf(v.w);
  ((ushort4*)dst)[idx] = o;
}

__global__ void pack_trg(const float* __restrict__ trg, ushort* __restrict__ packed, int n4){
  int idx = blockIdx.x*blockDim.x + threadIdx.x;
  if (idx >= n4) return;                 // n4 = B*T*E/4
  float4 v = ((const float4*)trg)[idx];
  int bt = idx >> 5, r = idx & 31;       // E/4 = 32
  ushort4 o; o.x = f2bf(v.x); o.y = f2bf(v.y); o.z = f2bf(v.z); o.w = f2bf(v.w);
  *(ushort4*)&packed[(long)bt*KPACK + r*4] = o;
}

__global__ void bsum_kernel(const float* __restrict__ a, const float* __restrict__ b,
                            float* __restrict__ o, int n){
  int idx = blockIdx.x*blockDim.x + threadIdx.x;
  if (idx < n) o[idx] = a[idx] + b[idx];
}

// ---------------- bridge ----------------
__global__ __launch_bounds__(512)
void bridge_kernel(const float* __restrict__ efh, const float* __restrict__ efc,
                   const float* __restrict__ bhw, const float* __restrict__ bhb,
                   const float* __restrict__ bcw, const float* __restrict__ bcb,
                   float* __restrict__ hb0, float* __restrict__ cws)
{
  int b = blockIdx.x, n = threadIdx.x;
  __shared__ __align__(16) float eh_l[1024];
  __shared__ __align__(16) float ec_l[1024];
  eh_l[n]       = efh[b*1024 + n];
  eh_l[n + 512] = efh[b*1024 + 512 + n];
  ec_l[n]       = efc[b*1024 + n];
  ec_l[n + 512] = efc[b*1024 + 512 + n];
  __syncthreads();
  const float4* wh = (const float4*)(bhw + (long)n*1024);
  const float4* wc = (const float4*)(bcw + (long)n*1024);
  float ah = bhb[n], ac = bcb[n];
  for (int i = 0; i < 256; ++i) {
    float4 w1 = wh[i]; float4 w2 = wc[i];
    const float* e1 = &eh_l[i*4]; const float* e2 = &ec_l[i*4];
    ah += w1.x*e1[0] + w1.y*e1[1] + w1.z*e1[2] + w1.w*e1[3];
    ac += w2.x*e2[0] + w2.y*e2[1] + w2.z*e2[2] + w2.w*e2[3];
  }
  hb0[b*512 + n] = ftanh(ah);
  cws[b*512 + n] = ftanh(ac);
}

// ---------------- MFMA BT-GEMM: C[m,n] = sum_k A[m,k]*Bt[n,k] ----------------
// outMode: 0 = f32, 1 = bf16, 2 = fp8(e4m3)
__global__ __launch_bounds__(256)
void gemm_bt(const ushort* __restrict__ A, int lda, long sA,
             const ushort* __restrict__ Bt, int ldb, long sB,
             void* __restrict__ Cout, int ldc, long sC, int K, int outMode)
{
  __shared__ __align__(16) ushort Al[128][40];
  __shared__ __align__(16) ushort Bl[128][40];
  int bz = blockIdx.z;
  const ushort* Ab = A + (long)bz*sA;
  const ushort* Bb = Bt + (long)bz*sB;
  int m0 = blockIdx.x*128, n0 = blockIdx.y*128;
  int tid = threadIdx.x;
  int lane = tid & 63, w = tid >> 6;
  int wm = w >> 1, wn = w & 1;
  f32x4 acc[4][4] = {};
  int frow = lane & 15, fk = (lane >> 4)*8;
  for (int k0 = 0; k0 < K; k0 += 32) {
    #pragma unroll
    for (int p = 0; p < 2; ++p) {
      int task = tid + p*256;
      int row = task >> 2, c8 = (task & 3)*8;
      uint4 va = *(const uint4*)(Ab + (long)(m0+row)*lda + k0 + c8);
      uint4 vb = *(const uint4*)(Bb + (long)(n0+row)*ldb + k0 + c8);
      *(uint4*)&Al[row][c8] = va;
      *(uint4*)&Bl[row][c8] = vb;
    }
    __syncthreads();
    short8_t af[4], bfr[4];
    #pragma unroll
    for (int mi = 0; mi < 4; ++mi) af[mi]  = *(const short8_t*)&Al[wm*64 + mi*16 + frow][fk];
    #pragma unroll
    for (int ni = 0; ni < 4; ++ni) bfr[ni] = *(const short8_t*)&Bl[wn*64 + ni*16 + frow][fk];
    #pragma unroll
    for (int mi = 0; mi < 4; ++mi)
      #pragma unroll
      for (int ni = 0; ni < 4; ++ni)
        acc[mi][ni] = __builtin_amdgcn_mfma_f32_16x16x32_bf16(af[mi], bfr[ni], acc[mi][ni], 0, 0, 0);
    __syncthreads();
  }
  int rbase = (lane >> 4)*4;
  int col = lane & 15;
  #pragma unroll
  for (int mi = 0; mi < 4; ++mi)
    #pragma unroll
    for (int ni = 0; ni < 4; ++ni)
      #pragma unroll
      for (int i = 0; i < 4; ++i) {
        int gm = m0 + wm*64 + mi*16 + rbase + i;
        int gn = n0 + wn*64 + ni*16 + col;
        float vv = acc[mi][ni][i];
        long off = (long)bz*sC + (long)gm*ldc + gn;
        if (outMode == 1)      ((ushort*)Cout)[off] = f2bf(vv);
        else if (outMode == 2) ((unsigned char*)Cout)[off] =
              (unsigned char)(__builtin_amdgcn_cvt_pk_fp8_f32(vv, 0.f, 0, false) & 0xFF);
        else                   ((float*)Cout)[off] = vv;
      }
}

// ---------------- qstep: q[b][n] = sum_k h[b][k] * Wq[n,k] ----------------
__global__ __launch_bounds__(512)
void qstep(const ushort* __restrict__ Wq, const float* __restrict__ hr,
           float* __restrict__ qbuf)
{
  __shared__ __align__(16) float h_s[512];
  int b = blockIdx.x, tid = threadIdx.x;
  h_s[tid] = hr[b*Hq + tid];
  __syncthreads();
  const ushort* wrow = Wq + (long)tid*Hq;
  float qa = 0.f;
  #pragma unroll 4
  for (int k = 0; k < 512; k += 8) {
    uint4 w4 = *(const uint4*)(wrow + k);
    const ushort* wu = (const ushort*)&w4;
    #pragma unroll
    for (int e = 0; e < 8; ++e) qa += h_s[k+e]*bf2f(wu[e]);
  }
  qbuf[b*Hq + tid] = qa;
}

// ---------------- scoreA: scores(fp8 pk) + exp + ctx/denom partials ----------------
// 512 blocks: (b, j8); 64 s per block; threads = 8 hq x 64 sl
__global__ __launch_bounds__(512)
void scoreA(const unsigned char* __restrict__ pk8,
            const ushort* __restrict__ ehb,
            const float* __restrict__ qbuf,
            const float* __restrict__ vatt,
            float* __restrict__ ctxp,
            float* __restrict__ denp)
{
  __shared__ __align__(16) float q_s[512];
  __shared__ __align__(16) float v_s[512];
  __shared__ __align__(16) float sred[512];
  __shared__ __align__(16) float e_s[64];
  int tid = threadIdx.x, blk = blockIdx.x;
  int b = blk >> 3, j8 = blk & 7, s0 = j8*64;
  q_s[tid] = qbuf[b*Hq + tid];
  v_s[tid] = vatt[tid];
  __syncthreads();
  int sl = tid & 63, hq = tid >> 6;   // 8 h-groups of 64
  {
    const unsigned char* pr = pk8 + ((long)b*Sq + s0 + sl)*Hq + hq*64;
    float p = 0.f;
    #pragma unroll
    for (int i = 0; i < 4; ++i) {
      uint4 w4 = *(const uint4*)(pr + i*16);
      const unsigned* uw = (const unsigned*)&w4;
      #pragma unroll
      for (int m = 0; m < 4; ++m) {
        unsigned u = uw[m];
        int hb = hq*64 + i*16 + m*4;
        p += v_s[hb+0]*ftanh(__builtin_amdgcn_cvt_f32_fp8(u,0) + q_s[hb+0]);
        p += v_s[hb+1]*ftanh(__builtin_amdgcn_cvt_f32_fp8(u,1) + q_s[hb+1]);
        p += v_s[hb+2]*ftanh(__builtin_amdgcn_cvt_f32_fp8(u,2) + q_s[hb+2]);
        p += v_s[hb+3]*ftanh(__builtin_amdgcn_cvt_f32_fp8(u,3) + q_s[hb+3]);
      }
    }
    sred[hq*64 + sl] = p;
  }
  __syncthreads();
  if (tid < 64) {
    float sc = 0.f;
    #pragma unroll
    for (int g = 0; g < 8; ++g) sc += sred[g*64 + tid];
    float e = __expf(sc);
    e_s[tid] = e;
    float r = e;
    #pragma unroll
    for (int off = 32; off; off >>= 1) r += __shfl_down(r, off);
    if (tid == 0) denp[b*8 + j8] = r;
  }
  __syncthreads();
  // unnormalized ctx partial over 64 s, thread owns k = 2*tid, 2*tid+1
  {
    const ushort* ep = ehb + ((long)b*Sq + s0)*H2q + tid*2;
    float a0 = 0.f, a1 = 0.f;
    #pragma unroll 4
    for (int s = 0; s < 64; ++s) {
      unsigned u = *(const unsigned*)(ep + (long)s*H2q);
      float es = e_s[s];
      a0 += es*bf2f((ushort)(u & 0xFFFF));
      a1 += es*bf2f((ushort)(u >> 16));
    }
    float* cp = ctxp + ((long)b*8 + j8)*1024 + tid*2;
    cp[0] = a0; cp[1] = a1;
  }
}

// ---------------- gatesB: normalize ctx + gates GEMM + LSTM ----------------
// 512 blocks: (c_bg of 8 b, c_rc of 64 row-chunks = 8 rows/gate); threads 512 = 16 ks x 32 row
__global__ __launch_bounds__(512)
void gatesB(int t, ushort* packed,
            const ushort* __restrict__ Wih, const ushort* __restrict__ Whh,
            const float* __restrict__ bsum, const float* __restrict__ hr,
            float* __restrict__ hw, float* __restrict__ cws,
            const float* __restrict__ ctxp, const float* __restrict__ denp,
            float* __restrict__ outs)
{
  __shared__ __align__(16) float  x_lds[8*KPACK];
  __shared__ __align__(16) ushort W_lds[32*128];
  __shared__ __align__(16) float  redc[4096];
  __shared__ __align__(16) float  g_lds[256];
  __shared__ __align__(16) float  rden[8];
  int tid = threadIdx.x, blk = blockIdx.x;
  int c_bg = blk >> 6, c_rc = blk & 63;

  if (tid < 8) {
    int gb = c_bg*8 + tid;
    float d = 0.f;
    #pragma unroll
    for (int j = 0; j < 8; ++j) d += denp[gb*8 + j];
    rden[tid] = frcp(d);
  }
  // trg region of x
  for (int task = tid; task < 128; task += 512) {
    int bb = task >> 4, c8 = task & 15;
    int gb = c_bg*8 + bb;
    uint4 vv = *(const uint4*)(packed + (long)(gb*Tq + t)*KPACK + c8*8);
    const ushort* uu = (const ushort*)&vv;
    #pragma unroll
    for (int e = 0; e < 8; ++e) x_lds[bb*KPACK + c8*8 + e] = bf2f(uu[e]);
  }
  // h region of x
  for (int task = tid; task < 4096; task += 512) {
    int bb = task >> 9, kk = task & 511;
    x_lds[bb*KPACK + 1152 + kk] = hr[(c_bg*8 + bb)*Hq + kk];
  }
  __syncthreads();   // rden ready
  // ctx region of x (normalize 8 partials); persist bf16 ctx for pre-GEMM
  for (int task = tid; task < 8192; task += 512) {
    int bb = task >> 10, kk = task & 1023;
    int gb = c_bg*8 + bb;
    const float* cp = ctxp + (long)gb*8*1024 + kk;
    float cv = 0.f;
    #pragma unroll
    for (int j = 0; j < 8; ++j) cv += cp[j*1024];
    cv *= rden[bb];
    x_lds[bb*KPACK + 128 + kk] = cv;
    if (c_rc == 0) packed[(long)(gb*Tq + t)*KPACK + 640 + kk] = f2bf(cv);
  }
  float acc[8] = {};
  int row = tid & 31, ks = tid >> 5;    // 32 rows, 16 k-slices of 8
  for (int kt = 0; kt < 13; ++kt) {
    __syncthreads();
    {
      int row8 = tid >> 4, c8 = (tid & 15)*8;
      int rr = (row8 >> 3)*512 + c_rc*8 + (row8 & 7);
      const ushort* wsrc = (kt < 9) ? (Wih + (long)rr*1152 + kt*128 + c8)
                                    : (Whh + (long)rr*512  + (kt-9)*128 + c8);
      uint4 w4 = *(const uint4*)wsrc;
      unsigned bo = (unsigned)(row8*256 + c8*2) ^ (unsigned)((row8 & 7) << 4);
      *(uint4*)((char*)W_lds + bo) = w4;
    }
    __syncthreads();
    {
      unsigned bo = (unsigned)(row*256 + ks*16) ^ (unsigned)((row & 7) << 4);
      uint4 w4 = *(const uint4*)((const char*)W_lds + bo);
      const ushort* wu = (const ushort*)&w4;
      float wf[8];
      #pragma unroll
      for (int e = 0; e < 8; ++e) wf[e] = bf2f(wu[e]);
      int xbase = kt*128 + ks*8;
      #pragma unroll
      for (int bb = 0; bb < 8; ++bb) {
        const float* xp = &x_lds[bb*KPACK + xbase];
        float4 x0 = *(const float4*)xp;
        float4 x1 = *(const float4*)(xp + 4);
        acc[bb] += wf[0]*x0.x + wf[1]*x0.y + wf[2]*x0.z + wf[3]*x0.w
                 + wf[4]*x1.x + wf[5]*x1.y + wf[6]*x1.z + wf[7]*x1.w;
      }
    }
  }
  __syncthreads();
  #pragma unroll
  for (int bb = 0; bb < 8; ++bb)
    redc[(ks*8 + bb)*32 + row] = acc[bb];
  __syncthreads();
  if (tid < 256) {
    int rl2 = tid & 31, bb = tid >> 5;
    float gvv = bsum[(rl2 >> 3)*512 + c_rc*8 + (rl2 & 7)];
    #pragma unroll
    for (int q2 = 0; q2 < 16; ++q2) gvv += redc[(q2*8 + bb)*32 + rl2];
    g_lds[bb*32 + rl2] = gvv;
  }
  __syncthreads();
  if (tid < 64) {
    int bb = tid >> 3, i2 = tid & 7;
    int gb = c_bg*8 + bb;
    int hd = c_rc*8 + i2;
    float gi = g_lds[bb*32 +  0 + i2];
    float gf = g_lds[bb*32 +  8 + i2];
    float gg = g_lds[bb*32 + 16 + i2];
    float go = g_lds[bb*32 + 24 + i2];
    float co = cws[gb*Hq + hd];
    float cn = fsig(gf)*co + fsig(gi)*ftanh(gg);
    float hn = fsig(go)*ftanh(cn);
    cws[gb*Hq + hd] = cn;
    hw[gb*Hq + hd] = hn;
    outs[(long)(gb*Tq + t)*Hq + hd] = hn;
    packed[(long)(gb*Tq + t)*KPACK + 128 + hd] = f2bf(hn);
  }
}

__global__ void epilogue_copy(const float* __restrict__ hb0, const float* __restrict__ cws,
                              float* __restrict__ dout){
  int idx = blockIdx.x*blockDim.x + threadIdx.x;
  if (idx < 32768) {
    dout[8388608 + idx] = hb0[idx];
    dout[8421376 + idx] = cws[idx];
  }
}

extern "C" void kernel_launch(void* const* d_in, const int* in_sizes, int n_in,
                              void* d_out, int out_size, void* d_ws, size_t ws_size,
                              hipStream_t stream)
{
  float* out = (float*)d_out;
  static const int expect[18] = {2097152,33554432,65536,65536,32768,16384,
                                 524288,262144,512,524288,512,524288,512,
                                 2359296,1048576,2048,2048,851968};
  if (n_in != 18 || out_size != 16842752) {
    bail_kernel<<<1, 256, 0, stream>>>(out, 33.0f); return;
  }
  for (int i = 0; i < 18; ++i) if (in_sizes[i] != expect[i]) {
    bail_kernel<<<1, 256, 0, stream>>>(out, 100.0f + i); return;
  }
  if (ws_size < 166207552ULL) { bail_kernel<<<1, 256, 0, stream>>>(out, 77.0f); return; }

  const float* trg  = (const float*)d_in[0];
  const float* eh   = (const float*)d_in[1];
  const float* efh  = (const float*)d_in[2];
  const float* efc  = (const float*)d_in[3];
  const float* Wk   = (const float*)d_in[6];
  const float* Wq   = (const float*)d_in[7];
  const float* v    = (const float*)d_in[8];
  const float* bhw  = (const float*)d_in[9];
  const float* bhb  = (const float*)d_in[10];
  const float* bcw  = (const float*)d_in[11];
  const float* bcb  = (const float*)d_in[12];
  const float* Wih  = (const float*)d_in[13];
  const float* Whh  = (const float*)d_in[14];
  const float* bih  = (const float*)d_in[15];
  const float* bhh  = (const float*)d_in[16];
  const float* Wpre = (const float*)d_in[17];
  char* ws = (char*)d_ws;

  ushort* ehb          = (ushort*)(ws + 0);
  unsigned char* pk8   = (unsigned char*)(ws + 67108864);
  ushort* packed       = (ushort*)(ws + 83886080);
  ushort* Wk_b         = (ushort*)(ws + 138412032);
  ushort* Wq_b         = (ushort*)(ws + 139460608);
  ushort* Wih_b        = (ushort*)(ws + 139984896);
  ushort* Whh_b        = (ushort*)(ws + 144703488);
  ushort* Wpre_b       = (ushort*)(ws + 146800640);
  float*  qbuf         = (float*)(ws + 148504576);
  float*  ctxp         = (float*)(ws + 148635648);
  float*  denp         = (float*)(ws + 150732800);
  float*  bsum         = (float*)(ws + 150734848);
  float*  hb0          = (float*)(ws + 150743040);
  float*  hb1          = (float*)(ws + 150874112);
  float*  cws          = (float*)(ws + 151005184);

  auto cb = [&](const float* s, ushort* d, int n){
    int n4 = n/4;
    conv_bf16<<<(n4 + 255)/256, 256, 0, stream>>>(s, d, n4);
  };
  cb(eh,   ehb,   64*512*1024);
  cb(Wk,   Wk_b,  512*1024);
  cb(Wq,   Wq_b,  512*512);
  cb(Wih,  Wih_b, 2048*1152);
  cb(Whh,  Whh_b, 2048*512);
  cb(Wpre, Wpre_b,512*1664);
  pack_trg<<<(524288 + 255)/256, 256, 0, stream>>>(trg, packed, 524288);
  bsum_kernel<<<8, 256, 0, stream>>>(bih, bhh, bsum, 2048);
  bridge_kernel<<<64, 512, 0, stream>>>(efh, efc, bhw, bhb, bcw, bcb, hb0, cws);
  // pk8[b][s][h] = sum_k eh[b,s,k]*Wk[h,k]  (fp8 e4m3 output)
  gemm_bt<<<dim3(4,4,64), 256, 0, stream>>>(ehb, 1024, 524288L, Wk_b, 1024, 0L,
                                            (void*)pk8, 512, 262144L, 1024, 2);

  for (int t = 0; t < 256; ++t) {
    const float* hr = (t & 1) ? hb1 : hb0;
    float*       hw = (t & 1) ? hb0 : hb1;
    qstep <<<64,  512, 0, stream>>>(Wq_b, hr, qbuf);
    scoreA<<<512, 512, 0, stream>>>(pk8, ehb, qbuf, v, ctxp, denp);
    gatesB<<<512, 512, 0, stream>>>(t, packed, Wih_b, Whh_b, bsum, hr, hw, cws,
                                    ctxp, denp, out);
  }

  epilogue_copy<<<128, 256, 0, stream>>>(hb0, cws, out);
  // pre[(b,t)][n] = sum_k packed[(b,t),k] * Wpre[n,k]  -> f32 output
  gemm_bt<<<dim3(128,4,1), 256, 0, stream>>>(packed, 1664, 0L, Wpre_b, 1664, 0L,
                                             (void*)(out + 8454144), 512, 0L, 1664, 0);
}

// Round 12
// 12326.656 us; speedup vs baseline: 3.5539x; 1.1658x over previous
//
#include <hip/hip_runtime.h>

#define Tq 256
#define Sq 512
#define Hq 512
#define H2q 1024
#define KPACK 1664   // trg(128) | outs(512) | ctx(1024)

typedef __attribute__((ext_vector_type(8))) short short8_t;
typedef __attribute__((ext_vector_type(4))) float f32x4;

__device__ __forceinline__ float bf2f(ushort u){ return __uint_as_float(((unsigned)u)<<16); }
__device__ __forceinline__ ushort f2bf(float f){
  unsigned u = __float_as_uint(f);
  u += 0x7FFFu + ((u>>16)&1u);
  return (ushort)(u>>16);
}
__device__ __forceinline__ float frcp(float x){ return __builtin_amdgcn_rcpf(x); }
__device__ __forceinline__ float ftanh(float x){
  x = fminf(fmaxf(x, -15.f), 15.f);
  float u = __expf(x + x);
  return (u - 1.f) * frcp(u + 1.f);
}
__device__ __forceinline__ float fsig(float x){
  return frcp(1.f + __expf(-x));
}

// ---------------- guard bail (f32 out) ----------------
__global__ void bail_kernel(float* out, float v){
  if (threadIdx.x < 256) out[threadIdx.x] = v;
}

// ---------------- conversion kernels ----------------
__global__ void conv_bf16(const float* __restrict__ src, ushort* __restrict__ dst, int n4){
  int idx = blockIdx.x*blockDim.x + threadIdx.x;
  if (idx >= n4) return;
  float4 v = ((const float4*)src)[idx];
  ushort4 o; o.x = f2bf(v.x); o.y = f2bf(v.y); o.z = f2bf(v.z); o.w = f2bf(v.w);
  ((ushort4*)dst)[idx] = o;
}

__global__ void pack_trg(const float* __restrict__ trg, ushort* __restrict__ packed, int n4){
  int idx = blockIdx.x*blockDim.x + threadIdx.x;
  if (idx >= n4) return;                 // n4 = B*T*E/4
  float4 v = ((const float4*)trg)[idx];
  int bt = idx >> 5, r = idx & 31;       // E/4 = 32
  ushort4 o; o.x = f2bf(v.x); o.y = f2bf(v.y); o.z = f2bf(v.z); o.w = f2bf(v.w);
  *(ushort4*)&packed[(long)bt*KPACK + r*4] = o;
}

__global__ void bsum_kernel(const float* __restrict__ a, const float* __restrict__ b,
                            float* __restrict__ o, int n){
  int idx = blockIdx.x*blockDim.x + threadIdx.x;
  if (idx < n) o[idx] = a[idx] + b[idx];
}

// ---------------- bridge ----------------
__global__ __launch_bounds__(512)
void bridge_kernel(const float* __restrict__ efh, const float* __restrict__ efc,
                   const float* __restrict__ bhw, const float* __restrict__ bhb,
                   const float* __restrict__ bcw, const float* __restrict__ bcb,
                   float* __restrict__ hb0, float* __restrict__ cws)
{
  int b = blockIdx.x, n = threadIdx.x;
  __shared__ __align__(16) float eh_l[1024];
  __shared__ __align__(16) float ec_l[1024];
  eh_l[n]       = efh[b*1024 + n];
  eh_l[n + 512] = efh[b*1024 + 512 + n];
  ec_l[n]       = efc[b*1024 + n];
  ec_l[n + 512] = efc[b*1024 + 512 + n];
  __syncthreads();
  const float4* wh = (const float4*)(bhw + (long)n*1024);
  const float4* wc = (const float4*)(bcw + (long)n*1024);
  float ah = bhb[n], ac = bcb[n];
  for (int i = 0; i < 256; ++i) {
    float4 w1 = wh[i]; float4 w2 = wc[i];
    const float* e1 = &eh_l[i*4]; const float* e2 = &ec_l[i*4];
    ah += w1.x*e1[0] + w1.y*e1[1] + w1.z*e1[2] + w1.w*e1[3];
    ac += w2.x*e2[0] + w2.y*e2[1] + w2.z*e2[2] + w2.w*e2[3];
  }
  hb0[b*512 + n] = ftanh(ah);
  cws[b*512 + n] = ftanh(ac);
}

// ---------------- MFMA BT-GEMM: C[m,n] = sum_k A[m,k]*Bt[n,k] ----------------
// outMode: 0 = f32, 1 = bf16, 2 = fp8(e4m3)
__global__ __launch_bounds__(256)
void gemm_bt(const ushort* __restrict__ A, int lda, long sA,
             const ushort* __restrict__ Bt, int ldb, long sB,
             void* __restrict__ Cout, int ldc, long sC, int K, int outMode)
{
  __shared__ __align__(16) ushort Al[128][40];
  __shared__ __align__(16) ushort Bl[128][40];
  int bz = blockIdx.z;
  const ushort* Ab = A + (long)bz*sA;
  const ushort* Bb = Bt + (long)bz*sB;
  int m0 = blockIdx.x*128, n0 = blockIdx.y*128;
  int tid = threadIdx.x;
  int lane = tid & 63, w = tid >> 6;
  int wm = w >> 1, wn = w & 1;
  f32x4 acc[4][4] = {};
  int frow = lane & 15, fk = (lane >> 4)*8;
  for (int k0 = 0; k0 < K; k0 += 32) {
    #pragma unroll
    for (int p = 0; p < 2; ++p) {
      int task = tid + p*256;
      int row = task >> 2, c8 = (task & 3)*8;
      uint4 va = *(const uint4*)(Ab + (long)(m0+row)*lda + k0 + c8);
      uint4 vb = *(const uint4*)(Bb + (long)(n0+row)*ldb + k0 + c8);
      *(uint4*)&Al[row][c8] = va;
      *(uint4*)&Bl[row][c8] = vb;
    }
    __syncthreads();
    short8_t af[4], bfr[4];
    #pragma unroll
    for (int mi = 0; mi < 4; ++mi) af[mi]  = *(const short8_t*)&Al[wm*64 + mi*16 + frow][fk];
    #pragma unroll
    for (int ni = 0; ni < 4; ++ni) bfr[ni] = *(const short8_t*)&Bl[wn*64 + ni*16 + frow][fk];
    #pragma unroll
    for (int mi = 0; mi < 4; ++mi)
      #pragma unroll
      for (int ni = 0; ni < 4; ++ni)
        acc[mi][ni] = __builtin_amdgcn_mfma_f32_16x16x32_bf16(af[mi], bfr[ni], acc[mi][ni], 0, 0, 0);
    __syncthreads();
  }
  int rbase = (lane >> 4)*4;
  int col = lane & 15;
  #pragma unroll
  for (int mi = 0; mi < 4; ++mi)
    #pragma unroll
    for (int ni = 0; ni < 4; ++ni)
      #pragma unroll
      for (int i = 0; i < 4; ++i) {
        int gm = m0 + wm*64 + mi*16 + rbase + i;
        int gn = n0 + wn*64 + ni*16 + col;
        float vv = acc[mi][ni][i];
        long off = (long)bz*sC + (long)gm*ldc + gn;
        if (outMode == 1)      ((ushort*)Cout)[off] = f2bf(vv);
        else if (outMode == 2) ((unsigned char*)Cout)[off] =
              (unsigned char)(__builtin_amdgcn_cvt_pk_fp8_f32(vv, 0.f, 0, false) & 0xFF);
        else                   ((float*)Cout)[off] = vv;
      }
}

// ---------------- qstep (t=0 only): q[b][n] = sum_k h[b][k] * Wq[n,k] ----------------
__global__ __launch_bounds__(512)
void qstep(const ushort* __restrict__ Wq, const float* __restrict__ hr,
           float* __restrict__ qbuf)
{
  __shared__ __align__(16) float h_s[512];
  int b = blockIdx.x, tid = threadIdx.x;
  h_s[tid] = hr[b*Hq + tid];
  __syncthreads();
  const ushort* wrow = Wq + (long)tid*Hq;
  float qa = 0.f;
  #pragma unroll 4
  for (int k = 0; k < 512; k += 8) {
    uint4 w4 = *(const uint4*)(wrow + k);
    const ushort* wu = (const ushort*)&w4;
    #pragma unroll
    for (int e = 0; e < 8; ++e) qa += h_s[k+e]*bf2f(wu[e]);
  }
  qbuf[b*Hq + tid] = qa;
}

// ---------------- scoreA: q-sum + scores(fp8 pk) + exp + ctx/denom partials ----------
// 512 blocks: (b, j8); 64 s per block; threads = 8 hq x 64 sl
__global__ __launch_bounds__(512)
void scoreA(const unsigned char* __restrict__ pk8,
            const ushort* __restrict__ ehb,
            const float* __restrict__ qpart,   // [b][64][512]
            const float* __restrict__ qbuf,    // used when useQbuf
            const float* __restrict__ vatt,
            float* __restrict__ ctxp,
            float* __restrict__ denp,
            int useQbuf)
{
  __shared__ __align__(16) float q_s[512];
  __shared__ __align__(16) float v_s[512];
  __shared__ __align__(16) float sred[512];
  __shared__ __align__(16) float e_s[64];
  int tid = threadIdx.x, blk = blockIdx.x;
  int b = blk >> 3, j8 = blk & 7, s0 = j8*64;
  if (useQbuf) {
    q_s[tid] = qbuf[b*Hq + tid];
  } else {
    const float* qp = qpart + (long)b*64*512 + tid;
    float qa = 0.f;
    #pragma unroll 8
    for (int c = 0; c < 64; ++c) qa += qp[c*512];
    q_s[tid] = qa;
  }
  v_s[tid] = vatt[tid];
  __syncthreads();
  int sl = tid & 63, hq = tid >> 6;   // 8 h-groups of 64
  {
    const unsigned char* pr = pk8 + ((long)b*Sq + s0 + sl)*Hq + hq*64;
    float p = 0.f;
    #pragma unroll
    for (int i = 0; i < 4; ++i) {
      uint4 w4 = *(const uint4*)(pr + i*16);
      const unsigned* uw = (const unsigned*)&w4;
      #pragma unroll
      for (int m = 0; m < 4; ++m) {
        unsigned u = uw[m];
        int hb = hq*64 + i*16 + m*4;
        p += v_s[hb+0]*ftanh(__builtin_amdgcn_cvt_f32_fp8(u,0) + q_s[hb+0]);
        p += v_s[hb+1]*ftanh(__builtin_amdgcn_cvt_f32_fp8(u,1) + q_s[hb+1]);
        p += v_s[hb+2]*ftanh(__builtin_amdgcn_cvt_f32_fp8(u,2) + q_s[hb+2]);
        p += v_s[hb+3]*ftanh(__builtin_amdgcn_cvt_f32_fp8(u,3) + q_s[hb+3]);
      }
    }
    sred[hq*64 + sl] = p;
  }
  __syncthreads();
  if (tid < 64) {
    float sc = 0.f;
    #pragma unroll
    for (int g = 0; g < 8; ++g) sc += sred[g*64 + tid];
    float e = __expf(sc);
    e_s[tid] = e;
    float r = e;
    #pragma unroll
    for (int off = 32; off; off >>= 1) r += __shfl_down(r, off);
    if (tid == 0) denp[b*8 + j8] = r;
  }
  __syncthreads();
  // unnormalized ctx partial over 64 s, thread owns k = 2*tid, 2*tid+1
  {
    const ushort* ep = ehb + ((long)b*Sq + s0)*H2q + tid*2;
    float a0 = 0.f, a1 = 0.f;
    #pragma unroll 4
    for (int s = 0; s < 64; ++s) {
      unsigned u = *(const unsigned*)(ep + (long)s*H2q);
      float es = e_s[s];
      a0 += es*bf2f((ushort)(u & 0xFFFF));
      a1 += es*bf2f((ushort)(u >> 16));
    }
    float* cp = ctxp + ((long)b*8 + j8)*1024 + tid*2;
    cp[0] = a0; cp[1] = a1;
  }
}

// ---------------- gatesB: ctx + gates GEMM (no-sync W loop) + LSTM + q-partials ----
// 512 blocks: (c_bg of 8 b, c_rc of 64 row-chunks = 8 rows/gate); threads 512 = 16 ks x 32 row
__global__ __launch_bounds__(512)
void gatesB(int t, ushort* packed,
            const ushort* __restrict__ Wih, const ushort* __restrict__ Whh,
            const ushort* __restrict__ Wq,
            const float* __restrict__ bsum, const float* __restrict__ hr,
            float* __restrict__ hw, float* __restrict__ cws,
            const float* __restrict__ ctxp, const float* __restrict__ denp,
            float* __restrict__ qpart,
            float* __restrict__ outs)
{
  __shared__ __align__(16) float  x_lds[8*KPACK];
  __shared__ __align__(16) float  redc[4096];
  __shared__ __align__(16) float  g_lds[256];
  __shared__ __align__(16) float  rden[8];
  __shared__ __align__(16) float  hn_s[64];
  int tid = threadIdx.x, blk = blockIdx.x;
  int c_bg = blk >> 6, c_rc = blk & 63;

  if (tid < 8) {
    int gb = c_bg*8 + tid;
    float d = 0.f;
    #pragma unroll
    for (int j = 0; j < 8; ++j) d += denp[gb*8 + j];
    rden[tid] = frcp(d);
  }
  // trg region of x
  for (int task = tid; task < 128; task += 512) {
    int bb = task >> 4, c8 = task & 15;
    int gb = c_bg*8 + bb;
    uint4 vv = *(const uint4*)(packed + (long)(gb*Tq + t)*KPACK + c8*8);
    const ushort* uu = (const ushort*)&vv;
    #pragma unroll
    for (int e = 0; e < 8; ++e) x_lds[bb*KPACK + c8*8 + e] = bf2f(uu[e]);
  }
  // h region of x
  for (int task = tid; task < 4096; task += 512) {
    int bb = task >> 9, kk = task & 511;
    x_lds[bb*KPACK + 1152 + kk] = hr[(c_bg*8 + bb)*Hq + kk];
  }
  __syncthreads();   // rden ready
  // ctx region of x (normalize 8 partials); persist bf16 ctx for pre-GEMM
  for (int task = tid; task < 8192; task += 512) {
    int bb = task >> 10, kk = task & 1023;
    int gb = c_bg*8 + bb;
    const float* cp = ctxp + (long)gb*8*1024 + kk;
    float cv = 0.f;
    #pragma unroll
    for (int j = 0; j < 8; ++j) cv += cp[j*1024];
    cv *= rden[bb];
    x_lds[bb*KPACK + 128 + kk] = cv;
    if (c_rc == 0) packed[(long)(gb*Tq + t)*KPACK + 640 + kk] = f2bf(cv);
  }
  __syncthreads();   // x ready
  float acc[8] = {};
  int row = tid & 31, ks = tid >> 5;    // 32 rows, 16 k-slices of 8
  int rr = (row >> 3)*512 + c_rc*8 + (row & 7);
  for (int kt = 0; kt < 13; ++kt) {
    const ushort* wsrc = (kt < 9) ? (Wih + (long)rr*1152 + kt*128 + ks*8)
                                  : (Whh + (long)rr*512  + (kt-9)*128 + ks*8);
    uint4 w4 = *(const uint4*)wsrc;
    const ushort* wu = (const ushort*)&w4;
    float wf[8];
    #pragma unroll
    for (int e = 0; e < 8; ++e) wf[e] = bf2f(wu[e]);
    int xbase = kt*128 + ks*8;
    #pragma unroll
    for (int bb = 0; bb < 8; ++bb) {
      const float* xp = &x_lds[bb*KPACK + xbase];
      float4 x0 = *(const float4*)xp;
      float4 x1 = *(const float4*)(xp + 4);
      acc[bb] += wf[0]*x0.x + wf[1]*x0.y + wf[2]*x0.z + wf[3]*x0.w
               + wf[4]*x1.x + wf[5]*x1.y + wf[6]*x1.z + wf[7]*x1.w;
    }
  }
  __syncthreads();
  #pragma unroll
  for (int bb = 0; bb < 8; ++bb)
    redc[(ks*8 + bb)*32 + row] = acc[bb];
  __syncthreads();
  if (tid < 256) {
    int rl2 = tid & 31, bb = tid >> 5;
    float gvv = bsum[(rl2 >> 3)*512 + c_rc*8 + (rl2 & 7)];
    #pragma unroll
    for (int q2 = 0; q2 < 16; ++q2) gvv += redc[(q2*8 + bb)*32 + rl2];
    g_lds[bb*32 + rl2] = gvv;
  }
  __syncthreads();
  if (tid < 64) {
    int bb = tid >> 3, i2 = tid & 7;
    int gb = c_bg*8 + bb;
    int hd = c_rc*8 + i2;
    float gi = g_lds[bb*32 +  0 + i2];
    float gf = g_lds[bb*32 +  8 + i2];
    float gg = g_lds[bb*32 + 16 + i2];
    float go = g_lds[bb*32 + 24 + i2];
    float co = cws[gb*Hq + hd];
    float cn = fsig(gf)*co + fsig(gi)*ftanh(gg);
    float hn = fsig(go)*ftanh(cn);
    cws[gb*Hq + hd] = cn;
    hw[gb*Hq + hd] = hn;
    outs[(long)(gb*Tq + t)*Hq + hd] = hn;
    packed[(long)(gb*Tq + t)*KPACK + 128 + hd] = f2bf(hn);
    hn_s[bb*8 + i2] = hn;
  }
  __syncthreads();
  // q-partials for step t+1: qpart[gb][c_rc][n=tid] = sum_i2 hn*Wq[n][c_rc*8+i2]
  {
    uint4 w4 = *(const uint4*)(Wq + (long)tid*Hq + c_rc*8);
    const ushort* wu = (const ushort*)&w4;
    float wf[8];
    #pragma unroll
    for (int e = 0; e < 8; ++e) wf[e] = bf2f(wu[e]);
    #pragma unroll
    for (int bb = 0; bb < 8; ++bb) {
      const float* hp = &hn_s[bb*8];
      float qa = wf[0]*hp[0] + wf[1]*hp[1] + wf[2]*hp[2] + wf[3]*hp[3]
               + wf[4]*hp[4] + wf[5]*hp[5] + wf[6]*hp[6] + wf[7]*hp[7];
      qpart[((long)(c_bg*8 + bb)*64 + c_rc)*512 + tid] = qa;
    }
  }
}

__global__ void epilogue_copy(const float* __restrict__ hb0, const float* __restrict__ cws,
                              float* __restrict__ dout){
  int idx = blockIdx.x*blockDim.x + threadIdx.x;
  if (idx < 32768) {
    dout[8388608 + idx] = hb0[idx];
    dout[8421376 + idx] = cws[idx];
  }
}

extern "C" void kernel_launch(void* const* d_in, const int* in_sizes, int n_in,
                              void* d_out, int out_size, void* d_ws, size_t ws_size,
                              hipStream_t stream)
{
  float* out = (float*)d_out;
  static const int expect[18] = {2097152,33554432,65536,65536,32768,16384,
                                 524288,262144,512,524288,512,524288,512,
                                 2359296,1048576,2048,2048,851968};
  if (n_in != 18 || out_size != 16842752) {
    bail_kernel<<<1, 256, 0, stream>>>(out, 33.0f); return;
  }
  for (int i = 0; i < 18; ++i) if (in_sizes[i] != expect[i]) {
    bail_kernel<<<1, 256, 0, stream>>>(out, 100.0f + i); return;
  }
  if (ws_size < 166207552ULL) { bail_kernel<<<1, 256, 0, stream>>>(out, 77.0f); return; }

  const float* trg  = (const float*)d_in[0];
  const float* eh   = (const float*)d_in[1];
  const float* efh  = (const float*)d_in[2];
  const float* efc  = (const float*)d_in[3];
  const float* Wk   = (const float*)d_in[6];
  const float* Wq   = (const float*)d_in[7];
  const float* v    = (const float*)d_in[8];
  const float* bhw  = (const float*)d_in[9];
  const float* bhb  = (const float*)d_in[10];
  const float* bcw  = (const float*)d_in[11];
  const float* bcb  = (const float*)d_in[12];
  const float* Wih  = (const float*)d_in[13];
  const float* Whh  = (const float*)d_in[14];
  const float* bih  = (const float*)d_in[15];
  const float* bhh  = (const float*)d_in[16];
  const float* Wpre = (const float*)d_in[17];
  char* ws = (char*)d_ws;

  ushort* ehb          = (ushort*)(ws + 0);
  unsigned char* pk8   = (unsigned char*)(ws + 67108864);
  ushort* packed       = (ushort*)(ws + 83886080);
  ushort* Wk_b         = (ushort*)(ws + 138412032);
  ushort* Wq_b         = (ushort*)(ws + 139460608);
  ushort* Wih_b        = (ushort*)(ws + 139984896);
  ushort* Whh_b        = (ushort*)(ws + 144703488);
  ushort* Wpre_b       = (ushort*)(ws + 146800640);
  float*  qbuf         = (float*)(ws + 148504576);
  float*  ctxp         = (float*)(ws + 148635648);
  float*  denp         = (float*)(ws + 150732800);
  float*  bsum         = (float*)(ws + 150734848);
  float*  hb0          = (float*)(ws + 150743040);
  float*  hb1          = (float*)(ws + 150874112);
  float*  cws          = (float*)(ws + 151005184);
  float*  qpart        = (float*)(ws + 151136256);   // 64*64*512*4 = 8 MB -> ends 159524864

  auto cb = [&](const float* s, ushort* d, int n){
    int n4 = n/4;
    conv_bf16<<<(n4 + 255)/256, 256, 0, stream>>>(s, d, n4);
  };
  cb(eh,   ehb,   64*512*1024);
  cb(Wk,   Wk_b,  512*1024);
  cb(Wq,   Wq_b,  512*512);
  cb(Wih,  Wih_b, 2048*1152);
  cb(Whh,  Whh_b, 2048*512);
  cb(Wpre, Wpre_b,512*1664);
  pack_trg<<<(524288 + 255)/256, 256, 0, stream>>>(trg, packed, 524288);
  bsum_kernel<<<8, 256, 0, stream>>>(bih, bhh, bsum, 2048);
  bridge_kernel<<<64, 512, 0, stream>>>(efh, efc, bhw, bhb, bcw, bcb, hb0, cws);
  // pk8[b][s][h] = sum_k eh[b,s,k]*Wk[h,k]  (fp8 e4m3 output)
  gemm_bt<<<dim3(4,4,64), 256, 0, stream>>>(ehb, 1024, 524288L, Wk_b, 1024, 0L,
                                            (void*)pk8, 512, 262144L, 1024, 2);
  qstep<<<64, 512, 0, stream>>>(Wq_b, hb0, qbuf);

  for (int t = 0; t < 256; ++t) {
    const float* hr = (t & 1) ? hb1 : hb0;
    float*       hw = (t & 1) ? hb0 : hb1;
    scoreA<<<512, 512, 0, stream>>>(pk8, ehb, qpart, qbuf, v, ctxp, denp, (t == 0) ? 1 : 0);
    gatesB<<<512, 512, 0, stream>>>(t, packed, Wih_b, Whh_b, Wq_b, bsum, hr, hw, cws,
                                    ctxp, denp, qpart, out);
  }

  epilogue_copy<<<128, 256, 0, stream>>>(hb0, cws, out);
  // pre[(b,t)][n] = sum_k packed[(b,t),k] * Wpre[n,k]  -> f32 output
  gemm_bt<<<dim3(128,4,1), 256, 0, stream>>>(packed, 1664, 0L, Wpre_b, 1664, 0L,
                                             (void*)(out + 8454144), 512, 0L, 1664, 0);
}